// Round 2
// baseline (929.843 us; speedup 1.0000x reference)
//
#include <hip/hip_runtime.h>
#include <math.h>

#define NA 50000
#define NP 1000000
#define OUTF 66
#define SCAN_BLOCKS 196  // ceil(50000/256)

// ---------------------------------------------------------------------------
// Workspace layout (4-byte elements), total 2,850,256 elems = 11.4 MB:
//   cnt     [NA]     int   pair count per atom
//   offs    [NA]     int   exclusive prefix (preserved)
//   curs    [NA]     int   scatter cursor (consumed)
//   blkS    [256]    int   per-block sums for the scan
//   sortedP [NP]     int   pair ids grouped by atom
//   S       [NA]     f32   sum of gsum over the atom's pairs
//   vec     [NA*32]  f32   vec_emb
// ---------------------------------------------------------------------------

__global__ void k_hist(const int* __restrict__ idxj, int* __restrict__ cnt) {
    int p = blockIdx.x * 256 + threadIdx.x;
    if (p < NP) atomicAdd(&cnt[idxj[p]], 1);
}

__global__ __launch_bounds__(256) void k_scanA(const int* __restrict__ cnt,
                                               int* __restrict__ blkS) {
    __shared__ int sh[256];
    int t = threadIdx.x;
    int i = blockIdx.x * 256 + t;
    sh[t] = (i < NA) ? cnt[i] : 0;
    __syncthreads();
    for (int d = 128; d > 0; d >>= 1) {
        if (t < d) sh[t] += sh[t + d];
        __syncthreads();
    }
    if (t == 0) blkS[blockIdx.x] = sh[0];
}

__global__ __launch_bounds__(256) void k_scanB(int* __restrict__ blkS) {
    __shared__ int sh[256];
    int t = threadIdx.x;
    sh[t] = (t < SCAN_BLOCKS) ? blkS[t] : 0;
    __syncthreads();
    for (int d = 1; d < 256; d <<= 1) {
        int x = (t >= d) ? sh[t - d] : 0;
        __syncthreads();
        sh[t] += x;
        __syncthreads();
    }
    int e = (t == 0) ? 0 : sh[t - 1];
    if (t < SCAN_BLOCKS) blkS[t] = e;
}

__global__ __launch_bounds__(256) void k_scanC(const int* __restrict__ cnt,
                                               const int* __restrict__ blkS,
                                               int* __restrict__ offs,
                                               int* __restrict__ curs) {
    __shared__ int sh[256];
    int t = threadIdx.x;
    int i = blockIdx.x * 256 + t;
    sh[t] = (i < NA) ? cnt[i] : 0;
    __syncthreads();
    for (int d = 1; d < 256; d <<= 1) {
        int x = (t >= d) ? sh[t - d] : 0;
        __syncthreads();
        sh[t] += x;
        __syncthreads();
    }
    int excl = ((t == 0) ? 0 : sh[t - 1]) + blkS[blockIdx.x];
    if (i < NA) { offs[i] = excl; curs[i] = excl; }
}

__global__ void k_scatter(const int* __restrict__ idxj, int* __restrict__ curs,
                          int* __restrict__ sortedP) {
    int p = blockIdx.x * 256 + threadIdx.x;
    if (p < NP) {
        int i = idxj[p];
        int pos = atomicAdd(&curs[i], 1);
        sortedP[pos] = p;
    }
}

// ---------------------------------------------------------------------------
// k_atoms: 8 atoms per block, 256 threads.
// Phase B: T[i,g,h] = sum_a emb[i,a]*agh[a,g,h] into LDS (agh L2-resident).
// Phase C: one wave per 2 atoms (sequential); T row hoisted to registers;
// per pair: gv (12 x float4 broadcast) + gs (4 x float4 broadcast), 48 FMA,
// accumulate vec/S in registers. No atomics, direct stores.
// ---------------------------------------------------------------------------
__global__ __launch_bounds__(256) void k_atoms(const float* __restrict__ emb,
                                               const float* __restrict__ agh,
                                               const float* __restrict__ gs,
                                               const float* __restrict__ gv,
                                               const int* __restrict__ sortedP,
                                               const int* __restrict__ offs,
                                               const int* __restrict__ cnt,
                                               float* __restrict__ S,
                                               float* __restrict__ vec) {
    __shared__ float embS[8][64];
    __shared__ float T_lds[8][32][20];  // [atom][h][g], g padded 16->20 (16B-aligned)
    const int t = threadIdx.x;
    const int atom0 = blockIdx.x * 8;

    for (int k = t; k < 8 * 64; k += 256)
        embS[k >> 6][k & 63] = emb[(size_t)(atom0 + (k >> 6)) * 64 + (k & 63)];
    __syncthreads();

    {   // T: thread owns gh columns t and t+256 for all 8 atoms
        float acc0[8], acc1[8];
#pragma unroll
        for (int at = 0; at < 8; ++at) { acc0[at] = 0.f; acc1[at] = 0.f; }
        const int gh0 = t, gh1 = t + 256;
        for (int a = 0; a < 64; ++a) {
            float w0 = agh[a * 512 + gh0];
            float w1 = agh[a * 512 + gh1];
#pragma unroll
            for (int at = 0; at < 8; ++at) {
                float e = embS[at][a];
                acc0[at] += e * w0;
                acc1[at] += e * w1;
            }
        }
        const int g0 = gh0 >> 5, h0 = gh0 & 31;
        const int g1 = gh1 >> 5, h1 = gh1 & 31;
#pragma unroll
        for (int at = 0; at < 8; ++at) {
            T_lds[at][h0][g0] = acc0[at];
            T_lds[at][h1][g1] = acc1[at];
        }
    }
    __syncthreads();

    const int wv = t >> 6, lane = t & 63;
    const int slot = lane >> 5, h = lane & 31;

    for (int at = 2 * wv; at < 2 * wv + 2; ++at) {
        const int i = atom0 + at;
        const int start = offs[i];
        const int n = cnt[i];

        float Tr[16];
#pragma unroll
        for (int g = 0; g < 16; ++g) Tr[g] = T_lds[at][h][g];

        float vacc = 0.f, gacc = 0.f;
        for (int it = 0; it < n; it += 2) {
            const int pi = it + slot;
            const bool ok = pi < n;
            if (ok) {
                const int p = sortedP[start + pi];
                // gv[p, 0:3, 0:16] — broadcast float4 loads (2 addrs per wave instr)
                float gr[48];
                const float4* gv4 = (const float4*)(gv + (size_t)p * 48);
#pragma unroll
                for (int q4 = 0; q4 < 12; ++q4) ((float4*)gr)[q4] = gv4[q4];

                float v0 = 0.f, v1 = 0.f, v2 = 0.f;
#pragma unroll
                for (int g = 0; g < 16; ++g) {
                    float tg = Tr[g];
                    v0 += gr[g] * tg;
                    v1 += gr[16 + g] * tg;
                    v2 += gr[32 + g] * tg;
                }
                vacc += v0 * v0 + v1 * v1 + v2 * v2;

                // gsum (redundant across the slot's 32 lanes — broadcast loads)
                const float4* gs4 = (const float4*)(gs + (size_t)p * 16);
                float4 ga = gs4[0], gb = gs4[1], gc = gs4[2], gd = gs4[3];
                gacc += (ga.x + ga.y + ga.z + ga.w) + (gb.x + gb.y + gb.z + gb.w) +
                        (gc.x + gc.y + gc.z + gc.w) + (gd.x + gd.y + gd.z + gd.w);
            }
        }
        float vtot = vacc + __shfl_xor(vacc, 32);
        float gtot = gacc + __shfl_xor(gacc, 32);
        if (lane < 32) vec[(size_t)i * 32 + h] = vtot;
        if (lane == 0) S[i] = gtot;
    }
}

// ---------------------------------------------------------------------------
// k_mlp: per-atom 3-layer MLP. msg = [a*S (64) | vec (32) | q*S (1)] (dead 32
// zero cols of W1 dropped). 32 atoms/block, 256 threads.
// ---------------------------------------------------------------------------
__global__ __launch_bounds__(256) void k_mlp(const float* __restrict__ emb,
                                             const float* __restrict__ q,
                                             const float* __restrict__ S,
                                             const float* __restrict__ vec,
                                             const float* __restrict__ W1,
                                             const float* __restrict__ b1,
                                             const float* __restrict__ W2,
                                             const float* __restrict__ b2,
                                             const float* __restrict__ W3,
                                             const float* __restrict__ b3,
                                             float* __restrict__ out) {
    __shared__ float msgS[32][97];
    __shared__ float h1S[32][128];
    __shared__ float h2S[32][128];
    const int t = threadIdx.x;
    const int atom0 = blockIdx.x * 32;

    for (int k = t; k < 32 * 97; k += 256) {
        int at = k / 97, c = k % 97;
        int i = atom0 + at;
        float val = 0.f;
        if (i < NA) {
            float s = S[i];
            if (c < 64) val = emb[(size_t)i * 64 + c] * s;
            else if (c < 96) val = vec[(size_t)i * 32 + (c - 64)];
            else val = q[i] * s;
        }
        msgS[at][c] = val;
    }
    __syncthreads();

    const int j = t & 127;
    const int base = (t >> 7) * 16;
    float acc[16];

#pragma unroll
    for (int r = 0; r < 16; ++r) acc[r] = b1[j];
    for (int k = 0; k < 97; ++k) {
        float w = W1[k * 128 + j];
#pragma unroll
        for (int r = 0; r < 16; ++r) acc[r] += msgS[base + r][k] * w;
    }
#pragma unroll
    for (int r = 0; r < 16; ++r) {
        float x = acc[r];
        h1S[base + r][j] = 0.5f * x * (1.f + erff(x * 0.70710678118654752f));
    }
    __syncthreads();

#pragma unroll
    for (int r = 0; r < 16; ++r) acc[r] = b2[j];
    for (int k = 0; k < 128; ++k) {
        float w = W2[k * 128 + j];
#pragma unroll
        for (int r = 0; r < 16; ++r) acc[r] += h1S[base + r][k] * w;
    }
#pragma unroll
    for (int r = 0; r < 16; ++r) {
        float x = acc[r];
        h2S[base + r][j] = 0.5f * x * (1.f + erff(x * 0.70710678118654752f));
    }
    __syncthreads();

    if (j < OUTF) {
#pragma unroll
        for (int r = 0; r < 16; ++r) acc[r] = b3[j];
        for (int k = 0; k < 128; ++k) {
            float w = W3[k * OUTF + j];
#pragma unroll
            for (int r = 0; r < 16; ++r) acc[r] += h2S[base + r][k] * w;
        }
#pragma unroll
        for (int r = 0; r < 16; ++r) {
            int i = atom0 + base + r;
            if (i < NA) {
                if (j == 0)
                    out[(size_t)NA * 64 + i] = acc[r];            // delta_q
                else if (j == 1)
                    out[(size_t)NA * 64 + NA + i] = acc[r];       // f
                else
                    out[(size_t)i * 64 + (j - 2)] = acc[r];       // delta_a
            }
        }
    }
}

extern "C" void kernel_launch(void* const* d_in, const int* in_sizes, int n_in,
                              void* d_out, int out_size, void* d_ws, size_t ws_size,
                              hipStream_t stream) {
    const float* emb = (const float*)d_in[0];
    const float* q   = (const float*)d_in[1];
    const float* gs  = (const float*)d_in[2];
    const float* gv  = (const float*)d_in[3];
    const float* agh = (const float*)d_in[4];
    const float* W1  = (const float*)d_in[5];
    const float* b1  = (const float*)d_in[6];
    const float* W2  = (const float*)d_in[7];
    const float* b2  = (const float*)d_in[8];
    const float* W3  = (const float*)d_in[9];
    const float* b3  = (const float*)d_in[10];
    const int* pairs = (const int*)d_in[11];
    const int* idxj  = pairs + NP;  // row 1 of pair_indices

    int*   cnt     = (int*)d_ws;
    int*   offs    = cnt + NA;
    int*   curs    = offs + NA;
    int*   blkS    = curs + NA;
    int*   sortedP = blkS + 256;
    float* S       = (float*)(sortedP + NP);
    float* vec     = S + NA;
    // total ws use: (3*NA + 256 + NP + NA + NA*32) * 4 = 11.4 MB

    hipMemsetAsync(cnt, 0, NA * sizeof(int), stream);
    k_hist<<<(NP + 255) / 256, 256, 0, stream>>>(idxj, cnt);
    k_scanA<<<SCAN_BLOCKS, 256, 0, stream>>>(cnt, blkS);
    k_scanB<<<1, 256, 0, stream>>>(blkS);
    k_scanC<<<SCAN_BLOCKS, 256, 0, stream>>>(cnt, blkS, offs, curs);
    k_scatter<<<(NP + 255) / 256, 256, 0, stream>>>(idxj, curs, sortedP);
    k_atoms<<<NA / 8, 256, 0, stream>>>(emb, agh, gs, gv, sortedP, offs, cnt, S, vec);
    k_mlp<<<(NA + 31) / 32, 256, 0, stream>>>(emb, q, S, vec,
                                              W1, b1, W2, b2, W3, b3,
                                              (float*)d_out);
}

// Round 3
// 806.143 us; speedup vs baseline: 1.1534x; 1.1534x over previous
//
#include <hip/hip_runtime.h>
#include <math.h>

#define NA 50000
#define NP 1000000
#define OUTF 66
#define SCAN_BLOCKS 196  // ceil(50000/256)

// ---------------------------------------------------------------------------
// Workspace (4-byte elems), ~11.4 MB total:
//   cnt[NA], offs[NA], curs[NA], blkS[256], sortedP[NP] (packed p<<3|at),
//   S[NA] f32, vec[NA*32] f32
// ---------------------------------------------------------------------------

__global__ void k_hist(const int* __restrict__ idxj, int* __restrict__ cnt) {
    int p = blockIdx.x * 256 + threadIdx.x;
    if (p < NP) atomicAdd(&cnt[idxj[p]], 1);
}

__global__ __launch_bounds__(256) void k_scanA(const int* __restrict__ cnt,
                                               int* __restrict__ blkS) {
    __shared__ int sh[256];
    int t = threadIdx.x;
    int i = blockIdx.x * 256 + t;
    sh[t] = (i < NA) ? cnt[i] : 0;
    __syncthreads();
    for (int d = 128; d > 0; d >>= 1) {
        if (t < d) sh[t] += sh[t + d];
        __syncthreads();
    }
    if (t == 0) blkS[blockIdx.x] = sh[0];
}

__global__ __launch_bounds__(256) void k_scanB(int* __restrict__ blkS) {
    __shared__ int sh[256];
    int t = threadIdx.x;
    sh[t] = (t < SCAN_BLOCKS) ? blkS[t] : 0;
    __syncthreads();
    for (int d = 1; d < 256; d <<= 1) {
        int x = (t >= d) ? sh[t - d] : 0;
        __syncthreads();
        sh[t] += x;
        __syncthreads();
    }
    int e = (t == 0) ? 0 : sh[t - 1];
    if (t < SCAN_BLOCKS) blkS[t] = e;
}

__global__ __launch_bounds__(256) void k_scanC(const int* __restrict__ cnt,
                                               const int* __restrict__ blkS,
                                               int* __restrict__ offs,
                                               int* __restrict__ curs) {
    __shared__ int sh[256];
    int t = threadIdx.x;
    int i = blockIdx.x * 256 + t;
    sh[t] = (i < NA) ? cnt[i] : 0;
    __syncthreads();
    for (int d = 1; d < 256; d <<= 1) {
        int x = (t >= d) ? sh[t - d] : 0;
        __syncthreads();
        sh[t] += x;
        __syncthreads();
    }
    int excl = ((t == 0) ? 0 : sh[t - 1]) + blkS[blockIdx.x];
    if (i < NA) { offs[i] = excl; curs[i] = excl; }
}

__global__ void k_scatter(const int* __restrict__ idxj, int* __restrict__ curs,
                          int* __restrict__ sortedP) {
    int p = blockIdx.x * 256 + threadIdx.x;
    if (p < NP) {
        int i = idxj[p];
        int pos = atomicAdd(&curs[i], 1);
        sortedP[pos] = (p << 3) | (i & 7);  // block-local atom id rides along
    }
}

// ---------------------------------------------------------------------------
// k_atoms: 8 atoms/block, 256 threads.
// Phase B: T[at][h][g] = sum_a emb*agh into LDS (layout [h][g], g padded 20).
// Phase C: lane quad per pair (16 pairs per load instruction!):
//   q = lane&3 owns h in [8q,8q+8); loads its pair's full gv row (12 x b128,
//   16 distinct rows per wave instr), T rows via aligned ds_read_b128,
//   e[h] -> ds_add_f32 into vecS; gs: one float4/lane + quad shuffle.
// ---------------------------------------------------------------------------
__global__ __launch_bounds__(256) void k_atoms(const float* __restrict__ emb,
                                               const float* __restrict__ agh,
                                               const float* __restrict__ gs,
                                               const float* __restrict__ gv,
                                               const int* __restrict__ sortedP,
                                               const int* __restrict__ offs,
                                               float* __restrict__ S,
                                               float* __restrict__ vec) {
    __shared__ float embS[8][64];
    __shared__ float T_lds[8][32][20];  // [atom][h][g] pad 16->20 (16B aligned rows)
    __shared__ float vecS[8][32];
    __shared__ float sS[8];
    const int t = threadIdx.x;
    const int atom0 = blockIdx.x * 8;

    vecS[t >> 5][t & 31] = 0.f;
    if (t < 8) sS[t] = 0.f;
    for (int k = t; k < 8 * 64; k += 256)
        embS[k >> 6][k & 63] = emb[(size_t)atom0 * 64 + k];
    __syncthreads();

    {   // ---- T phase: thread owns gh cols t and t+256 for all 8 atoms
        float acc0[8], acc1[8];
#pragma unroll
        for (int at = 0; at < 8; ++at) { acc0[at] = 0.f; acc1[at] = 0.f; }
        const int gh0 = t, gh1 = t + 256;
        for (int a = 0; a < 64; ++a) {
            float w0 = agh[a * 512 + gh0];
            float w1 = agh[a * 512 + gh1];
#pragma unroll
            for (int at = 0; at < 8; ++at) {
                float e = embS[at][a];
                acc0[at] += e * w0;
                acc1[at] += e * w1;
            }
        }
        const int g0 = gh0 >> 5, h0 = gh0 & 31;
        const int g1 = gh1 >> 5, h1 = gh1 & 31;
#pragma unroll
        for (int at = 0; at < 8; ++at) {
            T_lds[at][h0][g0] = acc0[at];
            T_lds[at][h1][g1] = acc1[at];
        }
    }
    __syncthreads();

    const int wv = t >> 6, lane = t & 63;
    const int pr = lane >> 2, q = lane & 3;
    const int hb = q * 8;
    const int start = offs[atom0];
    const int end = (atom0 + 8 < NA) ? offs[atom0 + 8] : NP;

    for (int k0 = start + wv * 16; k0 < end; k0 += 64) {
        const int k = k0 + pr;
        const bool ok = k < end;
        int pk = ok ? sortedP[k] : 0;
        const int p = pk >> 3, at = pk & 7;

        // gsum: one float4 per lane, reduce across the quad
        float gq = 0.f;
        if (ok) {
            float4 g4 = ((const float4*)gs)[(size_t)p * 4 + q];
            gq = (g4.x + g4.y) + (g4.z + g4.w);
        }
        gq += __shfl_xor(gq, 1);
        gq += __shfl_xor(gq, 2);
        if (ok && q == 0) atomicAdd(&sS[at], gq);

        if (ok) {
            float gvr[48];
            const float4* gv4 = (const float4*)(gv + (size_t)p * 48);
#pragma unroll
            for (int j = 0; j < 12; ++j) ((float4*)gvr)[j] = gv4[j];

#pragma unroll
            for (int hh = 0; hh < 8; ++hh) {
                const float4* Tr = (const float4*)&T_lds[at][hb + hh][0];
                float4 t0 = Tr[0], t1 = Tr[1], t2 = Tr[2], t3 = Tr[3];
                float Trow[16] = {t0.x, t0.y, t0.z, t0.w, t1.x, t1.y, t1.z, t1.w,
                                  t2.x, t2.y, t2.z, t2.w, t3.x, t3.y, t3.z, t3.w};
                float v0 = 0.f, v1 = 0.f, v2 = 0.f;
#pragma unroll
                for (int g = 0; g < 16; ++g) {
                    float tg = Trow[g];
                    v0 += gvr[g] * tg;
                    v1 += gvr[16 + g] * tg;
                    v2 += gvr[32 + g] * tg;
                }
                atomicAdd(&vecS[at][hb + hh], v0 * v0 + v1 * v1 + v2 * v2);
            }
        }
    }
    __syncthreads();

    vec[(size_t)(atom0 + (t >> 5)) * 32 + (t & 31)] = vecS[t >> 5][t & 31];
    if (t < 8) S[atom0 + t] = sS[t];
}

// ---------------------------------------------------------------------------
// k_mlp: 64 atoms/block, 256 threads, register tile 8 atoms x 4 j per thread.
// LDS: bufA (msg 97 / h2 128), bufB (h1 128), stride 132 (float4-aligned,
// 2-addr bank aliasing only). msg = [a*S | vec | q*S], dead 32 cols dropped.
// ---------------------------------------------------------------------------
#define MSTR 132
__global__ __launch_bounds__(256) void k_mlp(const float* __restrict__ emb,
                                             const float* __restrict__ q,
                                             const float* __restrict__ S,
                                             const float* __restrict__ vec,
                                             const float* __restrict__ W1,
                                             const float* __restrict__ b1,
                                             const float* __restrict__ W2,
                                             const float* __restrict__ b2,
                                             const float* __restrict__ W3,
                                             const float* __restrict__ b3,
                                             float* __restrict__ out) {
    __shared__ float bufA[64 * MSTR];
    __shared__ float bufB[64 * MSTR];
    const int t = threadIdx.x;
    const int atom0 = blockIdx.x * 64;

    for (int k = t; k < 64 * 97; k += 256) {
        int a = k / 97, c = k - a * 97;
        int i = atom0 + a;
        float val = 0.f;
        if (i < NA) {
            float s = S[i];
            if (c < 64) val = emb[(size_t)i * 64 + c] * s;
            else if (c < 96) val = vec[(size_t)i * 32 + (c - 64)];
            else val = q[i] * s;
        }
        bufA[a * MSTR + c] = val;
    }
    __syncthreads();

    const int jg = t & 31, ag = t >> 5;
    const int j0 = 4 * jg;
    const int abase = ag * 8;
    float acc[8][4];

    // ---- layer 1: K=97, bufA -> bufB
    {
        float4 bb = *(const float4*)&b1[j0];
#pragma unroll
        for (int a = 0; a < 8; ++a) {
            acc[a][0] = bb.x; acc[a][1] = bb.y; acc[a][2] = bb.z; acc[a][3] = bb.w;
        }
        for (int k4 = 0; k4 < 96; k4 += 4) {
            float4 w0 = *(const float4*)&W1[(k4 + 0) * 128 + j0];
            float4 w1 = *(const float4*)&W1[(k4 + 1) * 128 + j0];
            float4 w2 = *(const float4*)&W1[(k4 + 2) * 128 + j0];
            float4 w3 = *(const float4*)&W1[(k4 + 3) * 128 + j0];
#pragma unroll
            for (int a = 0; a < 8; ++a) {
                float4 m = *(const float4*)&bufA[(abase + a) * MSTR + k4];
                acc[a][0] += m.x * w0.x + m.y * w1.x + m.z * w2.x + m.w * w3.x;
                acc[a][1] += m.x * w0.y + m.y * w1.y + m.z * w2.y + m.w * w3.y;
                acc[a][2] += m.x * w0.z + m.y * w1.z + m.z * w2.z + m.w * w3.z;
                acc[a][3] += m.x * w0.w + m.y * w1.w + m.z * w2.w + m.w * w3.w;
            }
        }
        {   // k = 96 remainder
            float4 w = *(const float4*)&W1[96 * 128 + j0];
#pragma unroll
            for (int a = 0; a < 8; ++a) {
                float m = bufA[(abase + a) * MSTR + 96];
                acc[a][0] += m * w.x; acc[a][1] += m * w.y;
                acc[a][2] += m * w.z; acc[a][3] += m * w.w;
            }
        }
#pragma unroll
        for (int a = 0; a < 8; ++a) {
            float4 o;
            o.x = 0.5f * acc[a][0] * (1.f + erff(acc[a][0] * 0.70710678118654752f));
            o.y = 0.5f * acc[a][1] * (1.f + erff(acc[a][1] * 0.70710678118654752f));
            o.z = 0.5f * acc[a][2] * (1.f + erff(acc[a][2] * 0.70710678118654752f));
            o.w = 0.5f * acc[a][3] * (1.f + erff(acc[a][3] * 0.70710678118654752f));
            *(float4*)&bufB[(abase + a) * MSTR + j0] = o;
        }
    }
    __syncthreads();

    // ---- layer 2: K=128, bufB -> bufA
    {
        float4 bb = *(const float4*)&b2[j0];
#pragma unroll
        for (int a = 0; a < 8; ++a) {
            acc[a][0] = bb.x; acc[a][1] = bb.y; acc[a][2] = bb.z; acc[a][3] = bb.w;
        }
        for (int k4 = 0; k4 < 128; k4 += 4) {
            float4 w0 = *(const float4*)&W2[(k4 + 0) * 128 + j0];
            float4 w1 = *(const float4*)&W2[(k4 + 1) * 128 + j0];
            float4 w2 = *(const float4*)&W2[(k4 + 2) * 128 + j0];
            float4 w3 = *(const float4*)&W2[(k4 + 3) * 128 + j0];
#pragma unroll
            for (int a = 0; a < 8; ++a) {
                float4 m = *(const float4*)&bufB[(abase + a) * MSTR + k4];
                acc[a][0] += m.x * w0.x + m.y * w1.x + m.z * w2.x + m.w * w3.x;
                acc[a][1] += m.x * w0.y + m.y * w1.y + m.z * w2.y + m.w * w3.y;
                acc[a][2] += m.x * w0.z + m.y * w1.z + m.z * w2.z + m.w * w3.z;
                acc[a][3] += m.x * w0.w + m.y * w1.w + m.z * w2.w + m.w * w3.w;
            }
        }
#pragma unroll
        for (int a = 0; a < 8; ++a) {
            float4 o;
            o.x = 0.5f * acc[a][0] * (1.f + erff(acc[a][0] * 0.70710678118654752f));
            o.y = 0.5f * acc[a][1] * (1.f + erff(acc[a][1] * 0.70710678118654752f));
            o.z = 0.5f * acc[a][2] * (1.f + erff(acc[a][2] * 0.70710678118654752f));
            o.w = 0.5f * acc[a][3] * (1.f + erff(acc[a][3] * 0.70710678118654752f));
            *(float4*)&bufA[(abase + a) * MSTR + j0] = o;
        }
    }
    __syncthreads();

    // ---- layer 3: K=128, bufA -> out (66 cols; jg>16 idle)
    if (j0 < OUTF) {
#pragma unroll
        for (int a = 0; a < 8; ++a) {
            acc[a][0] = b3[j0];
            acc[a][1] = (j0 + 1 < OUTF) ? b3[j0 + 1] : 0.f;
            acc[a][2] = (j0 + 2 < OUTF) ? b3[j0 + 2] : 0.f;
            acc[a][3] = (j0 + 3 < OUTF) ? b3[j0 + 3] : 0.f;
        }
        for (int k = 0; k < 128; ++k) {
            float w0 = W3[k * OUTF + j0];
            float w1 = (j0 + 1 < OUTF) ? W3[k * OUTF + j0 + 1] : 0.f;
            float w2 = (j0 + 2 < OUTF) ? W3[k * OUTF + j0 + 2] : 0.f;
            float w3 = (j0 + 3 < OUTF) ? W3[k * OUTF + j0 + 3] : 0.f;
#pragma unroll
            for (int a = 0; a < 8; ++a) {
                float m = bufA[(abase + a) * MSTR + k];
                acc[a][0] += m * w0; acc[a][1] += m * w1;
                acc[a][2] += m * w2; acc[a][3] += m * w3;
            }
        }
#pragma unroll
        for (int a = 0; a < 8; ++a) {
            int i = atom0 + abase + a;
            if (i < NA) {
#pragma unroll
                for (int c = 0; c < 4; ++c) {
                    int j = j0 + c;
                    if (j < OUTF) {
                        if (j == 0)
                            out[(size_t)NA * 64 + i] = acc[a][c];        // delta_q
                        else if (j == 1)
                            out[(size_t)NA * 64 + NA + i] = acc[a][c];   // f
                        else
                            out[(size_t)i * 64 + (j - 2)] = acc[a][c];   // delta_a
                    }
                }
            }
        }
    }
}

extern "C" void kernel_launch(void* const* d_in, const int* in_sizes, int n_in,
                              void* d_out, int out_size, void* d_ws, size_t ws_size,
                              hipStream_t stream) {
    const float* emb = (const float*)d_in[0];
    const float* q   = (const float*)d_in[1];
    const float* gs  = (const float*)d_in[2];
    const float* gv  = (const float*)d_in[3];
    const float* agh = (const float*)d_in[4];
    const float* W1  = (const float*)d_in[5];
    const float* b1  = (const float*)d_in[6];
    const float* W2  = (const float*)d_in[7];
    const float* b2  = (const float*)d_in[8];
    const float* W3  = (const float*)d_in[9];
    const float* b3  = (const float*)d_in[10];
    const int* pairs = (const int*)d_in[11];
    const int* idxj  = pairs + NP;  // row 1 of pair_indices

    int*   cnt     = (int*)d_ws;
    int*   offs    = cnt + NA;
    int*   curs    = offs + NA;
    int*   blkS    = curs + NA;
    int*   sortedP = blkS + 256;
    float* S       = (float*)(sortedP + NP);
    float* vec     = S + NA;

    hipMemsetAsync(cnt, 0, NA * sizeof(int), stream);
    k_hist<<<(NP + 255) / 256, 256, 0, stream>>>(idxj, cnt);
    k_scanA<<<SCAN_BLOCKS, 256, 0, stream>>>(cnt, blkS);
    k_scanB<<<1, 256, 0, stream>>>(blkS);
    k_scanC<<<SCAN_BLOCKS, 256, 0, stream>>>(cnt, blkS, offs, curs);
    k_scatter<<<(NP + 255) / 256, 256, 0, stream>>>(idxj, curs, sortedP);
    k_atoms<<<NA / 8, 256, 0, stream>>>(emb, agh, gs, gv, sortedP, offs, S, vec);
    k_mlp<<<(NA + 63) / 64, 256, 0, stream>>>(emb, q, S, vec,
                                              W1, b1, W2, b2, W3, b3,
                                              (float*)d_out);
}

// Round 4
// 785.708 us; speedup vs baseline: 1.1834x; 1.0260x over previous
//
#include <hip/hip_runtime.h>
#include <math.h>

#define NA 50000
#define NP 1000000
#define OUTF 66
#define SCAN_BLOCKS 196  // ceil(50000/256)
#define ATB 16           // atoms per k_atoms block (NA = 16*3125 exactly)
#define TSTR 516         // T atom stride (floats): 512+4 -> lanes spread banks

// ---------------------------------------------------------------------------
// Workspace (4-byte elems), ~11.4 MB:
//   cnt[NA], offs[NA], curs[NA], blkS[256], sortedP[NP] (packed p<<4 | i&15),
//   S[NA] f32, vec[NA*32] f32
// ---------------------------------------------------------------------------

__global__ void k_hist(const int* __restrict__ idxj, int* __restrict__ cnt) {
    int p = blockIdx.x * 256 + threadIdx.x;
    if (p < NP) atomicAdd(&cnt[idxj[p]], 1);
}

__global__ __launch_bounds__(256) void k_scanA(const int* __restrict__ cnt,
                                               int* __restrict__ blkS) {
    __shared__ int sh[256];
    int t = threadIdx.x;
    int i = blockIdx.x * 256 + t;
    sh[t] = (i < NA) ? cnt[i] : 0;
    __syncthreads();
    for (int d = 128; d > 0; d >>= 1) {
        if (t < d) sh[t] += sh[t + d];
        __syncthreads();
    }
    if (t == 0) blkS[blockIdx.x] = sh[0];
}

__global__ __launch_bounds__(256) void k_scanB(int* __restrict__ blkS) {
    __shared__ int sh[256];
    int t = threadIdx.x;
    sh[t] = (t < SCAN_BLOCKS) ? blkS[t] : 0;
    __syncthreads();
    for (int d = 1; d < 256; d <<= 1) {
        int x = (t >= d) ? sh[t - d] : 0;
        __syncthreads();
        sh[t] += x;
        __syncthreads();
    }
    int e = (t == 0) ? 0 : sh[t - 1];
    if (t < SCAN_BLOCKS) blkS[t] = e;
}

__global__ __launch_bounds__(256) void k_scanC(const int* __restrict__ cnt,
                                               const int* __restrict__ blkS,
                                               int* __restrict__ offs,
                                               int* __restrict__ curs) {
    __shared__ int sh[256];
    int t = threadIdx.x;
    int i = blockIdx.x * 256 + t;
    sh[t] = (i < NA) ? cnt[i] : 0;
    __syncthreads();
    for (int d = 1; d < 256; d <<= 1) {
        int x = (t >= d) ? sh[t - d] : 0;
        __syncthreads();
        sh[t] += x;
        __syncthreads();
    }
    int excl = ((t == 0) ? 0 : sh[t - 1]) + blkS[blockIdx.x];
    if (i < NA) { offs[i] = excl; curs[i] = excl; }
}

__global__ void k_scatter(const int* __restrict__ idxj, int* __restrict__ curs,
                          int* __restrict__ sortedP) {
    int p = blockIdx.x * 256 + threadIdx.x;
    if (p < NP) {
        int i = idxj[p];
        int pos = atomicAdd(&curs[i], 1);
        sortedP[pos] = (p << 4) | (i & 15);  // block-local atom id rides along
    }
}

// ---------------------------------------------------------------------------
// k_atoms: 16 atoms/block, 256 threads.
// Phase B: T[at][h][g] into LDS, atom stride 516 (=4 mod 32: conflict-free
// reads later; same-atom lanes broadcast).
// Phase C: ONE LANE = ONE PAIR. Lane loads its pair's gv row (12 x dwordx4,
// 64 distinct rows per wave instr), loops h=0..31 reading T via ds_read_b128
// (bank-spread), e -> pair-merged ds_add into vecS.
// ---------------------------------------------------------------------------
__global__ __launch_bounds__(256) void k_atoms(const float* __restrict__ emb,
                                               const float* __restrict__ agh,
                                               const float* __restrict__ gs,
                                               const float* __restrict__ gv,
                                               const int* __restrict__ sortedP,
                                               const int* __restrict__ offs,
                                               float* __restrict__ S,
                                               float* __restrict__ vec) {
    __shared__ float T_lds[ATB * TSTR];   // 33.0 KB
    __shared__ float embS[ATB * 64];      // 4 KB
    __shared__ float vecS[ATB * 33];      // stride 33 -> ds_add banks spread
    __shared__ float sS[ATB];
    const int t = threadIdx.x;
    const int atom0 = blockIdx.x * ATB;

    for (int k = t; k < ATB * 33; k += 256) vecS[k] = 0.f;
    if (t < ATB) sS[t] = 0.f;
    for (int k = t; k < ATB * 64; k += 256) embS[k] = emb[(size_t)atom0 * 64 + k];
    __syncthreads();

    {   // ---- T phase: thread owns agh columns c0 = t, c1 = t+256
        float acc0[ATB], acc1[ATB];
#pragma unroll
        for (int at = 0; at < ATB; ++at) { acc0[at] = 0.f; acc1[at] = 0.f; }
        const int c0 = t, c1 = t + 256;
        for (int a = 0; a < 64; ++a) {
            float w0 = agh[a * 512 + c0];
            float w1 = agh[a * 512 + c1];
#pragma unroll
            for (int at = 0; at < ATB; ++at) {
                float e = embS[at * 64 + a];
                acc0[at] += e * w0;
                acc1[at] += e * w1;
            }
        }
        const int g0 = c0 >> 5, h0 = c0 & 31;   // col = g*32 + h
        const int g1 = c1 >> 5, h1 = c1 & 31;
#pragma unroll
        for (int at = 0; at < ATB; ++at) {
            T_lds[at * TSTR + h0 * 16 + g0] = acc0[at];
            T_lds[at * TSTR + h1 * 16 + g1] = acc1[at];
        }
    }
    __syncthreads();

    const int lane = t & 63;
    const int start = offs[atom0];
    const int end = (blockIdx.x + 1 < 3125) ? offs[atom0 + ATB] : NP;

    for (int kb = start; kb < end; kb += 256) {   // uniform trip count
        const int k = kb + t;
        const bool ok = (k < end);
        const int pk = ok ? sortedP[k] : 0;
        const int p = ok ? (pk >> 4) : 0;
        const int at = pk & 15;
        const int atm = ok ? at : (64 + lane);    // unique -> never merges

        // neighbor-merge setup (sorted pairs cluster by atom)
        const int atn = __shfl_xor(atm, 1);
        const bool same = (atn == atm);
        const bool flush = (!same) || ((lane & 1) == 0);

        // gv row -> registers (64 distinct rows per wave instruction)
        float gvr[48];
        const float4* gv4 = (const float4*)(gv + (size_t)p * 48);
#pragma unroll
        for (int j = 0; j < 12; ++j) ((float4*)gvr)[j] = gv4[j];

        // gsum
        const float4* gs4 = (const float4*)(gs + (size_t)p * 16);
        float4 ga = gs4[0], gb = gs4[1], gc = gs4[2], gd = gs4[3];
        float gq = (ga.x + ga.y + ga.z + ga.w) + (gb.x + gb.y + gb.z + gb.w) +
                   (gc.x + gc.y + gc.z + gc.w) + (gd.x + gd.y + gd.z + gd.w);
        float gqn = __shfl_xor(gq, 1);
        float gqm = gq + (same ? gqn : 0.f);
        if (ok && flush) atomicAdd(&sS[at], gqm);

        const float* Tb = &T_lds[at * TSTR];
#pragma unroll 4
        for (int h = 0; h < 32; ++h) {
            const float4* Tr = (const float4*)(Tb + h * 16);
            float4 t0 = Tr[0], t1 = Tr[1], t2 = Tr[2], t3 = Tr[3];
            float v0, v1, v2;
            v0  = gvr[0]  * t0.x; v1  = gvr[16] * t0.x; v2  = gvr[32] * t0.x;
            v0 += gvr[1]  * t0.y; v1 += gvr[17] * t0.y; v2 += gvr[33] * t0.y;
            v0 += gvr[2]  * t0.z; v1 += gvr[18] * t0.z; v2 += gvr[34] * t0.z;
            v0 += gvr[3]  * t0.w; v1 += gvr[19] * t0.w; v2 += gvr[35] * t0.w;
            v0 += gvr[4]  * t1.x; v1 += gvr[20] * t1.x; v2 += gvr[36] * t1.x;
            v0 += gvr[5]  * t1.y; v1 += gvr[21] * t1.y; v2 += gvr[37] * t1.y;
            v0 += gvr[6]  * t1.z; v1 += gvr[22] * t1.z; v2 += gvr[38] * t1.z;
            v0 += gvr[7]  * t1.w; v1 += gvr[23] * t1.w; v2 += gvr[39] * t1.w;
            v0 += gvr[8]  * t2.x; v1 += gvr[24] * t2.x; v2 += gvr[40] * t2.x;
            v0 += gvr[9]  * t2.y; v1 += gvr[25] * t2.y; v2 += gvr[41] * t2.y;
            v0 += gvr[10] * t2.z; v1 += gvr[26] * t2.z; v2 += gvr[42] * t2.z;
            v0 += gvr[11] * t2.w; v1 += gvr[27] * t2.w; v2 += gvr[43] * t2.w;
            v0 += gvr[12] * t3.x; v1 += gvr[28] * t3.x; v2 += gvr[44] * t3.x;
            v0 += gvr[13] * t3.y; v1 += gvr[29] * t3.y; v2 += gvr[45] * t3.y;
            v0 += gvr[14] * t3.z; v1 += gvr[30] * t3.z; v2 += gvr[46] * t3.z;
            v0 += gvr[15] * t3.w; v1 += gvr[31] * t3.w; v2 += gvr[47] * t3.w;
            float e = v0 * v0 + v1 * v1 + v2 * v2;
            float en = __shfl_xor(e, 1);
            float em = e + (same ? en : 0.f);
            if (ok && flush) atomicAdd(&vecS[at * 33 + h], em);
        }
    }
    __syncthreads();

    for (int k = t; k < ATB * 32; k += 256) {
        int a = k >> 5, h = k & 31;
        vec[(size_t)(atom0 + a) * 32 + h] = vecS[a * 33 + h];
    }
    if (t < ATB) S[atom0 + t] = sS[t];
}

// ---------------------------------------------------------------------------
// k_mlp: 64 atoms/block, 256 threads, register tile 8 atoms x 4 j per thread.
// ---------------------------------------------------------------------------
#define MSTR 132
__global__ __launch_bounds__(256) void k_mlp(const float* __restrict__ emb,
                                             const float* __restrict__ q,
                                             const float* __restrict__ S,
                                             const float* __restrict__ vec,
                                             const float* __restrict__ W1,
                                             const float* __restrict__ b1,
                                             const float* __restrict__ W2,
                                             const float* __restrict__ b2,
                                             const float* __restrict__ W3,
                                             const float* __restrict__ b3,
                                             float* __restrict__ out) {
    __shared__ float bufA[64 * MSTR];
    __shared__ float bufB[64 * MSTR];
    const int t = threadIdx.x;
    const int atom0 = blockIdx.x * 64;

    for (int k = t; k < 64 * 97; k += 256) {
        int a = k / 97, c = k - a * 97;
        int i = atom0 + a;
        float val = 0.f;
        if (i < NA) {
            float s = S[i];
            if (c < 64) val = emb[(size_t)i * 64 + c] * s;
            else if (c < 96) val = vec[(size_t)i * 32 + (c - 64)];
            else val = q[i] * s;
        }
        bufA[a * MSTR + c] = val;
    }
    __syncthreads();

    const int jg = t & 31, ag = t >> 5;
    const int j0 = 4 * jg;
    const int abase = ag * 8;
    float acc[8][4];

    // ---- layer 1: K=97, bufA -> bufB
    {
        float4 bb = *(const float4*)&b1[j0];
#pragma unroll
        for (int a = 0; a < 8; ++a) {
            acc[a][0] = bb.x; acc[a][1] = bb.y; acc[a][2] = bb.z; acc[a][3] = bb.w;
        }
        for (int k4 = 0; k4 < 96; k4 += 4) {
            float4 w0 = *(const float4*)&W1[(k4 + 0) * 128 + j0];
            float4 w1 = *(const float4*)&W1[(k4 + 1) * 128 + j0];
            float4 w2 = *(const float4*)&W1[(k4 + 2) * 128 + j0];
            float4 w3 = *(const float4*)&W1[(k4 + 3) * 128 + j0];
#pragma unroll
            for (int a = 0; a < 8; ++a) {
                float4 m = *(const float4*)&bufA[(abase + a) * MSTR + k4];
                acc[a][0] += m.x * w0.x + m.y * w1.x + m.z * w2.x + m.w * w3.x;
                acc[a][1] += m.x * w0.y + m.y * w1.y + m.z * w2.y + m.w * w3.y;
                acc[a][2] += m.x * w0.z + m.y * w1.z + m.z * w2.z + m.w * w3.z;
                acc[a][3] += m.x * w0.w + m.y * w1.w + m.z * w2.w + m.w * w3.w;
            }
        }
        {   // k = 96 remainder
            float4 w = *(const float4*)&W1[96 * 128 + j0];
#pragma unroll
            for (int a = 0; a < 8; ++a) {
                float m = bufA[(abase + a) * MSTR + 96];
                acc[a][0] += m * w.x; acc[a][1] += m * w.y;
                acc[a][2] += m * w.z; acc[a][3] += m * w.w;
            }
        }
#pragma unroll
        for (int a = 0; a < 8; ++a) {
            float4 o;
            o.x = 0.5f * acc[a][0] * (1.f + erff(acc[a][0] * 0.70710678118654752f));
            o.y = 0.5f * acc[a][1] * (1.f + erff(acc[a][1] * 0.70710678118654752f));
            o.z = 0.5f * acc[a][2] * (1.f + erff(acc[a][2] * 0.70710678118654752f));
            o.w = 0.5f * acc[a][3] * (1.f + erff(acc[a][3] * 0.70710678118654752f));
            *(float4*)&bufB[(abase + a) * MSTR + j0] = o;
        }
    }
    __syncthreads();

    // ---- layer 2: K=128, bufB -> bufA
    {
        float4 bb = *(const float4*)&b2[j0];
#pragma unroll
        for (int a = 0; a < 8; ++a) {
            acc[a][0] = bb.x; acc[a][1] = bb.y; acc[a][2] = bb.z; acc[a][3] = bb.w;
        }
        for (int k4 = 0; k4 < 128; k4 += 4) {
            float4 w0 = *(const float4*)&W2[(k4 + 0) * 128 + j0];
            float4 w1 = *(const float4*)&W2[(k4 + 1) * 128 + j0];
            float4 w2 = *(const float4*)&W2[(k4 + 2) * 128 + j0];
            float4 w3 = *(const float4*)&W2[(k4 + 3) * 128 + j0];
#pragma unroll
            for (int a = 0; a < 8; ++a) {
                float4 m = *(const float4*)&bufB[(abase + a) * MSTR + k4];
                acc[a][0] += m.x * w0.x + m.y * w1.x + m.z * w2.x + m.w * w3.x;
                acc[a][1] += m.x * w0.y + m.y * w1.y + m.z * w2.y + m.w * w3.y;
                acc[a][2] += m.x * w0.z + m.y * w1.z + m.z * w2.z + m.w * w3.z;
                acc[a][3] += m.x * w0.w + m.y * w1.w + m.z * w2.w + m.w * w3.w;
            }
        }
#pragma unroll
        for (int a = 0; a < 8; ++a) {
            float4 o;
            o.x = 0.5f * acc[a][0] * (1.f + erff(acc[a][0] * 0.70710678118654752f));
            o.y = 0.5f * acc[a][1] * (1.f + erff(acc[a][1] * 0.70710678118654752f));
            o.z = 0.5f * acc[a][2] * (1.f + erff(acc[a][2] * 0.70710678118654752f));
            o.w = 0.5f * acc[a][3] * (1.f + erff(acc[a][3] * 0.70710678118654752f));
            *(float4*)&bufA[(abase + a) * MSTR + j0] = o;
        }
    }
    __syncthreads();

    // ---- layer 3: K=128, bufA -> out (66 cols; jg>16 idle)
    if (j0 < OUTF) {
#pragma unroll
        for (int a = 0; a < 8; ++a) {
            acc[a][0] = b3[j0];
            acc[a][1] = (j0 + 1 < OUTF) ? b3[j0 + 1] : 0.f;
            acc[a][2] = (j0 + 2 < OUTF) ? b3[j0 + 2] : 0.f;
            acc[a][3] = (j0 + 3 < OUTF) ? b3[j0 + 3] : 0.f;
        }
        for (int k = 0; k < 128; ++k) {
            float w0 = W3[k * OUTF + j0];
            float w1 = (j0 + 1 < OUTF) ? W3[k * OUTF + j0 + 1] : 0.f;
            float w2 = (j0 + 2 < OUTF) ? W3[k * OUTF + j0 + 2] : 0.f;
            float w3 = (j0 + 3 < OUTF) ? W3[k * OUTF + j0 + 3] : 0.f;
#pragma unroll
            for (int a = 0; a < 8; ++a) {
                float m = bufA[(abase + a) * MSTR + k];
                acc[a][0] += m * w0; acc[a][1] += m * w1;
                acc[a][2] += m * w2; acc[a][3] += m * w3;
            }
        }
#pragma unroll
        for (int a = 0; a < 8; ++a) {
            int i = atom0 + abase + a;
            if (i < NA) {
#pragma unroll
                for (int c = 0; c < 4; ++c) {
                    int j = j0 + c;
                    if (j < OUTF) {
                        if (j == 0)
                            out[(size_t)NA * 64 + i] = acc[a][c];        // delta_q
                        else if (j == 1)
                            out[(size_t)NA * 64 + NA + i] = acc[a][c];   // f
                        else
                            out[(size_t)i * 64 + (j - 2)] = acc[a][c];   // delta_a
                    }
                }
            }
        }
    }
}

extern "C" void kernel_launch(void* const* d_in, const int* in_sizes, int n_in,
                              void* d_out, int out_size, void* d_ws, size_t ws_size,
                              hipStream_t stream) {
    const float* emb = (const float*)d_in[0];
    const float* q   = (const float*)d_in[1];
    const float* gs  = (const float*)d_in[2];
    const float* gv  = (const float*)d_in[3];
    const float* agh = (const float*)d_in[4];
    const float* W1  = (const float*)d_in[5];
    const float* b1  = (const float*)d_in[6];
    const float* W2  = (const float*)d_in[7];
    const float* b2  = (const float*)d_in[8];
    const float* W3  = (const float*)d_in[9];
    const float* b3  = (const float*)d_in[10];
    const int* pairs = (const int*)d_in[11];
    const int* idxj  = pairs + NP;  // row 1 of pair_indices

    int*   cnt     = (int*)d_ws;
    int*   offs    = cnt + NA;
    int*   curs    = offs + NA;
    int*   blkS    = curs + NA;
    int*   sortedP = blkS + 256;
    float* S       = (float*)(sortedP + NP);
    float* vec     = S + NA;

    hipMemsetAsync(cnt, 0, NA * sizeof(int), stream);
    k_hist<<<(NP + 255) / 256, 256, 0, stream>>>(idxj, cnt);
    k_scanA<<<SCAN_BLOCKS, 256, 0, stream>>>(cnt, blkS);
    k_scanB<<<1, 256, 0, stream>>>(blkS);
    k_scanC<<<SCAN_BLOCKS, 256, 0, stream>>>(cnt, blkS, offs, curs);
    k_scatter<<<(NP + 255) / 256, 256, 0, stream>>>(idxj, curs, sortedP);
    k_atoms<<<NA / ATB, 256, 0, stream>>>(emb, agh, gs, gv, sortedP, offs, S, vec);
    k_mlp<<<(NA + 63) / 64, 256, 0, stream>>>(emb, q, S, vec,
                                              W1, b1, W2, b2, W3, b3,
                                              (float*)d_out);
}